// Round 6
// baseline (152.486 us; speedup 1.0000x reference)
//
#include <hip/hip_runtime.h>
#include <hip/hip_bf16.h>
#include <cstdint>

#define NPOS 1568   // 8*14*14
#define NQPAD 1664  // 13 * 128
#define NKVT 25     // kv tiles of 64
#define DHEAD 128
#define DIM 256
// scale * log2(e): softmax in log2 domain
#define SCALE_Q (0.08838834764831845f * 1.4426950408889634f)

typedef __bf16 bf16x8 __attribute__((ext_vector_type(8)));
typedef float f32x4 __attribute__((ext_vector_type(4)));
typedef float f32x16 __attribute__((ext_vector_type(16)));
typedef unsigned short u16;
typedef u16 u16x8 __attribute__((ext_vector_type(8)));

__device__ __forceinline__ unsigned cvtpk(float a, float b) {
  unsigned r;
  asm("v_cvt_pk_bf16_f32 %0, %1, %2" : "=v"(r) : "v"(a), "v"(b));
  return r;
}

__device__ __forceinline__ void gload_lds16(const void* g, void* s) {
  __builtin_amdgcn_global_load_lds(
      (const __attribute__((address_space(1))) unsigned*)g,
      (__attribute__((address_space(3))) unsigned*)s, 16, 0, 0);
}

__device__ __forceinline__ f32x16 zero16() {
  f32x16 v;
#pragma unroll
  for (int i = 0; i < 16; ++i) v[i] = 0.f;
  return v;
}

// ---------------- emb: [1568][128] f32 ----------------
__global__ __launch_bounds__(256) void emb_kernel(
    const float* __restrict__ pf, const float* __restrict__ ph,
    const float* __restrict__ pw, float* __restrict__ emb) {
  int idx = blockIdx.x * 256 + threadIdx.x;
  int pos = idx >> 7, d = idx & 127;
  int jf = pos / 196; int r = pos - jf * 196; int jh = r / 14; int jw = r - jh * 14;
  emb[idx] = pf[jf * 128 + d] + ph[jh * 128 + d] + pw[jw * 128 + d];
}

// ---------------- wconv: W f32 -> bf16, same layout [1536][256] ----------------
__global__ __launch_bounds__(256) void wconv_kernel(
    const float* __restrict__ W, u16* __restrict__ Wbf) {
  int i8 = (blockIdx.x * 256 + threadIdx.x) * 8;
  float4 f0 = *(const float4*)(W + i8);
  float4 f1 = *(const float4*)(W + i8 + 4);
  union { unsigned u[4]; u16x8 v; } o;
  o.u[0] = cvtpk(f0.x, f0.y); o.u[1] = cvtpk(f0.z, f0.w);
  o.u[2] = cvtpk(f1.x, f1.y); o.u[3] = cvtpk(f1.z, f1.w);
  *(u16x8*)(Wbf + i8) = o.v;
}

// ---------------- ftrans: fmap [b][c][pos] f32 -> fmapT [b][pos(pad 1664)][c] bf16 ----------------
// grid (26, 4, 8)
__global__ __launch_bounds__(256) void ftrans_kernel(
    const float* __restrict__ fmap, u16* __restrict__ fmapT) {
  __shared__ float t[64][68];
  const int tid = threadIdx.x;
  const int pos0 = blockIdx.x * 64, c0 = blockIdx.y * 64, b = blockIdx.z;
  const int cl = tid >> 3, p8 = (tid & 7) * 8;
  const bool pv = (pos0 + p8) < NPOS;   // NPOS % 8 == 0 -> all-or-nothing
#pragma unroll
  for (int half = 0; half < 2; ++half) {
    int c = cl + half * 32;
    float4 f0 = {0.f, 0.f, 0.f, 0.f}, f1 = {0.f, 0.f, 0.f, 0.f};
    if (pv) {
      const float* src = fmap + ((size_t)(b * DIM + c0 + c)) * NPOS + pos0 + p8;
      f0 = *(const float4*)src;
      f1 = *(const float4*)(src + 4);
    }
    *(float4*)&t[c][p8] = f0;
    *(float4*)&t[c][p8 + 4] = f1;
  }
  __syncthreads();
  const int pl = tid >> 2, c16 = (tid & 3) * 16;
  const int gpos = pos0 + pl;
  union { unsigned u[8]; } o;
  if (gpos < NPOS) {
#pragma unroll
    for (int i = 0; i < 8; ++i) o.u[i] = cvtpk(t[c16 + 2 * i][pl], t[c16 + 2 * i + 1][pl]);
  } else {
#pragma unroll
    for (int i = 0; i < 8; ++i) o.u[i] = 0;
  }
  u16* dst = fmapT + ((size_t)b * NQPAD + gpos) * DIM + c0 + c16;
  *(uint4*)(dst) = *(uint4*)&o.u[0];
  *(uint4*)(dst + 8) = *(uint4*)&o.u[4];
}

// ---------------- projection: 128x128 tiles, frags direct from L2 ----------------
// flat grid 1248: b = wid&7 (XCD-local), then 12 o-tiles x 13 pos-tiles.
__global__ __launch_bounds__(256, 4) void proj_kernel(
    const u16* __restrict__ Wbf, const u16* __restrict__ fmapT,
    const float* __restrict__ emb, u16* __restrict__ qws, char* __restrict__ tiles) {
  __shared__ float ot[64][132];
  const int tid = threadIdx.x;
  const int lane = tid & 63, w = tid >> 6;
  const int l15 = lane & 15, g = lane >> 4;
  const int wid = blockIdx.x;
  const int b = wid & 7;
  const int gq = wid >> 3;              // 0..155
  const int o0 = (gq / 13) * 128;
  const int pos0 = (gq % 13) * 128;
  const int wo = (w & 1) * 64, wp = (w >> 1) * 64;

  f32x4 acc[4][4];
#pragma unroll
  for (int i = 0; i < 4; ++i)
#pragma unroll
    for (int j = 0; j < 4; ++j) acc[i][j] = (f32x4){0.f, 0.f, 0.f, 0.f};

  const u16* Ab = Wbf + (size_t)(o0 + wo + l15) * DIM + g * 8;
  const u16* Bb = fmapT + ((size_t)b * NQPAD + pos0 + wp + l15) * DIM + g * 8;
#pragma unroll 2
  for (int c0 = 0; c0 < DIM; c0 += 32) {
    bf16x8 a[4], bb[4];
#pragma unroll
    for (int t = 0; t < 4; ++t) a[t] = *(const bf16x8*)(Ab + (size_t)t * 16 * DIM + c0);
#pragma unroll
    for (int t = 0; t < 4; ++t) bb[t] = *(const bf16x8*)(Bb + (size_t)t * 16 * DIM + c0);
#pragma unroll
    for (int i = 0; i < 4; ++i)
#pragma unroll
      for (int j = 0; j < 4; ++j)
        acc[i][j] = __builtin_amdgcn_mfma_f32_16x16x32_bf16(a[i], bb[j], acc[i][j], 0, 0, 0);
  }

  const int sec = o0 >> 9, head = (o0 >> 7) & 3, bh = b * 4 + head;

  if (sec < 2) {   // q,k: transpose to [pos][o] chunks of 64 pos
#pragma unroll
    for (int ph = 0; ph < 2; ++ph) {
      __syncthreads();
      if (wp == ph * 64) {
#pragma unroll
        for (int i = 0; i < 4; ++i)
#pragma unroll
          for (int j = 0; j < 4; ++j)
#pragma unroll
            for (int r = 0; r < 4; ++r)
              ot[j * 16 + l15][wo + i * 16 + 4 * g + r] = acc[i][j][r];
      }
      __syncthreads();
      const int pl = tid >> 2, c32 = (tid & 3) * 32;
      const int gpos = pos0 + ph * 64 + pl;
      float v[32];
#pragma unroll
      for (int i = 0; i < 32; ++i) v[i] = ot[pl][c32 + i];
      if (sec == 0) {
#pragma unroll
        for (int q = 0; q < 4; ++q) {
          union { unsigned u[4]; u16x8 h; } o8;
#pragma unroll
          for (int i = 0; i < 4; ++i)
            o8.u[i] = cvtpk(v[q * 8 + 2 * i] * SCALE_Q, v[q * 8 + 2 * i + 1] * SCALE_Q);
          *(u16x8*)(qws + ((size_t)bh * NQPAD + gpos) * DHEAD + c32 + q * 8) = o8.h;
        }
      } else {
        if (gpos < NKVT * 64) {
          if (gpos < NPOS) {
            const float* eb = emb + (size_t)gpos * DHEAD + c32;
#pragma unroll
            for (int i = 0; i < 8; ++i) {
              float4 e = *(const float4*)(eb + i * 4);
              v[i * 4 + 0] += e.x; v[i * 4 + 1] += e.y;
              v[i * 4 + 2] += e.z; v[i * 4 + 3] += e.w;
            }
          }
          const int jt = gpos >> 6, jl = gpos & 63;
          char* base = tiles + ((size_t)(bh * NKVT + jt)) * 32768 + jl * 256;
          const int swz = (jl & 7) << 4;
#pragma unroll
          for (int q = 0; q < 4; ++q) {
            union { unsigned u[4]; u16x8 h; } o8;
#pragma unroll
            for (int i = 0; i < 4; ++i)
              o8.u[i] = cvtpk(v[q * 8 + 2 * i], v[q * 8 + 2 * i + 1]);
            *(u16x8*)(base + (((c32 + q * 8) * 2) ^ swz)) = o8.h;
          }
        }
      }
    }
  } else {         // v: keep [d][pos], chunks of 64 d
#pragma unroll
    for (int ch = 0; ch < 2; ++ch) {
      __syncthreads();
      if (wo == ch * 64) {
#pragma unroll
        for (int i = 0; i < 4; ++i)
#pragma unroll
          for (int j = 0; j < 4; ++j)
#pragma unroll
            for (int r = 0; r < 4; ++r)
              ot[i * 16 + 4 * g + r][wp + j * 16 + l15] = acc[i][j][r];
      }
      __syncthreads();
      const int dl = tid >> 2, p32 = (tid & 3) * 32;
      const int d = ch * 64 + dl;
      const int gp = pos0 + p32;
      float v[32];
#pragma unroll
      for (int i = 0; i < 32; ++i) v[i] = ot[dl][p32 + i];
      if (gp < NKVT * 64) {
        const int jt = gp >> 6, jl0 = gp & 63;
        char* base = tiles + ((size_t)(bh * NKVT + jt)) * 32768 + 16384 + d * 128;
        const int swz = (d & 7) << 4;
#pragma unroll
        for (int q = 0; q < 4; ++q) {
          union { unsigned u[4]; u16x8 h; } o8;
#pragma unroll
          for (int i = 0; i < 4; ++i)
            o8.u[i] = cvtpk(v[q * 8 + 2 * i], v[q * 8 + 2 * i + 1]);
          *(u16x8*)(base + (((jl0 + q * 8) * 2) ^ swz)) = o8.h;
        }
      }
    }
  }
}

// ---------------- attention: 8 waves (2 j-groups x 4 q-waves), swapped 32x32 MFMA ----------------
// flat grid 416: bh = (wid&7)*4 + (wid>>3)/13 (4 bh per XCD), bx = (wid>>3)%13.
__global__ __launch_bounds__(512, 4) void attn_kernel(
    const u16* __restrict__ qws, const char* __restrict__ tiles,
    float* __restrict__ out) {
  __shared__ char smem[65536];
  const int tid = threadIdx.x;
  const int lane = tid & 63, w = tid >> 6;
  const int qw = w & 3, grp = w >> 2;
  const int l31 = lane & 31, hi = lane >> 5;
  const int wid = blockIdx.x;
  const int bh = (wid & 7) * 4 + (wid >> 3) / 13;
  const int bx = (wid >> 3) % 13;
  const int b = bh >> 2, h = bh & 3;
  const int q0 = bx * 128;
  // rho: swap bits 2<->3 of l31 (involution); makes S^T D-layout == B-slot order
  const int rho = (l31 & 0x13) | ((l31 & 4) << 1) | ((l31 & 8) >> 1);
  const int krow = grp * 32 + rho;
  const int jb = grp * 64;   // j-local byte base in V^T rows

  bf16x8 qf[8];
  {
    const u16* qp = qws + ((size_t)bh * NQPAD + q0 + qw * 32 + l31) * DHEAD + 8 * hi;
#pragma unroll
    for (int kk = 0; kk < 8; ++kk) qf[kk] = *(const bf16x8*)(qp + kk * 16);
  }

  f32x16 oacc[4];
#pragma unroll
  for (int dt = 0; dt < 4; ++dt) oacc[dt] = zero16();
  float m = -1e30f, l = 0.f;

  const size_t tbase = (size_t)bh * NKVT * 32768;

  {  // prologue: stage tile 0
    const char* src = tiles + tbase + w * 4096 + lane * 16;
    char* dst = smem + w * 4096;
#pragma unroll
    for (int i = 0; i < 4; ++i) gload_lds16(src + i * 1024, dst + i * 1024);
  }
  __syncthreads();

  int cur = 0;
  for (int jt = 0; jt < NKVT; ++jt) {
    if (jt + 1 < NKVT) {
      const char* src = tiles + tbase + (size_t)(jt + 1) * 32768 + w * 4096 + lane * 16;
      char* dst = smem + (cur ^ 1) * 32768 + w * 4096;
#pragma unroll
      for (int i = 0; i < 4; ++i) gload_lds16(src + i * 1024, dst + i * 1024);
    }
    const char* kt = smem + cur * 32768;
    const char* vt = kt + 16384;

    if (grp == 0 || jt < NKVT - 1) {   // tail tile: only rows 0..31 valid (group 0)
      f32x16 sc = zero16();
      {
        const int swz = (krow & 7) << 4;
#pragma unroll
        for (int kk = 0; kk < 8; ++kk) {
          bf16x8 ka = *(const bf16x8*)(kt + krow * 256 + ((kk * 32 + 16 * hi) ^ swz));
          sc = __builtin_amdgcn_mfma_f32_32x32x16_bf16(ka, qf[kk], sc, 0, 0, 0);
        }
      }
      float pm = -1e30f;
#pragma unroll
      for (int i = 0; i < 16; ++i) pm = fmaxf(pm, sc[i]);
      pm = fmaxf(pm, __shfl_xor(pm, 32));
      if (!__all(pm <= m + 8.f)) {   // defer-max
        float mn = fmaxf(m, pm);
        float al = exp2f(m - mn);
        m = mn;
        l *= al;
#pragma unroll
        for (int dt = 0; dt < 4; ++dt)
#pragma unroll
          for (int i = 0; i < 16; ++i) oacc[dt][i] *= al;
      }
      float lac = 0.f;
#pragma unroll
      for (int i = 0; i < 16; ++i) { sc[i] = exp2f(sc[i] - m); lac += sc[i]; }
      l += lac;

      union { unsigned u[4]; bf16x8 v; } pb0, pb1;
      pb0.u[0] = cvtpk(sc[0], sc[1]);   pb0.u[1] = cvtpk(sc[2], sc[3]);
      pb0.u[2] = cvtpk(sc[4], sc[5]);   pb0.u[3] = cvtpk(sc[6], sc[7]);
      pb1.u[0] = cvtpk(sc[8], sc[9]);   pb1.u[1] = cvtpk(sc[10], sc[11]);
      pb1.u[2] = cvtpk(sc[12], sc[13]); pb1.u[3] = cvtpk(sc[14], sc[15]);
#pragma unroll
      for (int dt = 0; dt < 4; ++dt) {
        const int row = dt * 32 + l31, swz = (row & 7) << 4;
        bf16x8 va0 = *(const bf16x8*)(vt + row * 128 + ((jb + 16 * hi) ^ swz));
        oacc[dt] = __builtin_amdgcn_mfma_f32_32x32x16_bf16(va0, pb0.v, oacc[dt], 0, 0, 0);
        bf16x8 va1 = *(const bf16x8*)(vt + row * 128 + ((jb + 32 + 16 * hi) ^ swz));
        oacc[dt] = __builtin_amdgcn_mfma_f32_32x32x16_bf16(va1, pb1.v, oacc[dt], 0, 0, 0);
      }
    }
    __syncthreads();
    cur ^= 1;
  }

  // ---- combine group 1 into group 0 (flash merge), then store ----
  // CRITICAL: l is a per-lane PARTIAL denominator (this hi-half's 16 j-slots
  // per tile); combine across the hi pair before merging groups.
  float lt = l + __shfl_xor(l, 32);
  float* ml = (float*)smem;               // [4 qw][64 lane][2]
  float* cx = (float*)(smem + 4096);      // [32 reg][256 (qw,lane)]
  if (grp == 1) {
    ml[(qw * 64 + lane) * 2 + 0] = m;
    ml[(qw * 64 + lane) * 2 + 1] = lt;
  }
  __syncthreads();
  float fA = 0.f, fB = 0.f;
  if (grp == 0) {
    float mB = ml[(qw * 64 + lane) * 2 + 0];
    float lB = ml[(qw * 64 + lane) * 2 + 1];
    float ms = fmaxf(m, mB);
    float aA = exp2f(m - ms), aB = exp2f(mB - ms);
    float inv = 1.f / (lt * aA + lB * aB);
    fA = aA * inv; fB = aB * inv;
  }
  const int q = q0 + qw * 32 + l31;
  float* ob = out + (size_t)(b * 512 + h * 128) * NPOS + q;
#pragma unroll
  for (int ch = 0; ch < 2; ++ch) {
    __syncthreads();
    if (grp == 1) {
#pragma unroll
      for (int k = 0; k < 2; ++k)
#pragma unroll
        for (int i = 0; i < 16; ++i)
          cx[(k * 16 + i) * 256 + qw * 64 + lane] = oacc[ch * 2 + k][i];
    }
    __syncthreads();
    if (grp == 0 && q < NPOS) {
#pragma unroll
      for (int k = 0; k < 2; ++k) {
        const int dt = ch * 2 + k;
#pragma unroll
        for (int r = 0; r < 16; ++r) {
          float vB = cx[(k * 16 + r) * 256 + qw * 64 + lane];
          float vo = oacc[dt][r] * fA + vB * fB;
          int d = dt * 32 + (r & 3) + 8 * (r >> 2) + 4 * hi;
          ob[(size_t)d * NPOS] = vo;
        }
      }
    }
  }
}

extern "C" void kernel_launch(void* const* d_in, const int* in_sizes, int n_in,
                              void* d_out, int out_size, void* d_ws, size_t ws_size,
                              hipStream_t stream) {
  const float* fmap = (const float*)d_in[0];
  const float* W    = (const float*)d_in[1];
  const float* pf   = (const float*)d_in[2];
  const float* ph   = (const float*)d_in[3];
  const float* pw   = (const float*)d_in[4];
  float* out = (float*)d_out;

  // ws holds only qws + tiles (39.85 MB, within the R3-proven budget).
  char* ws = (char*)d_ws;
  const size_t QSZ = (size_t)32 * NQPAD * DHEAD * 2;   // 13,631,488
  u16* qws    = (u16*)ws;
  char* tiles = ws + QSZ;

  // Aux buffers live in d_out-as-scratch (8.4 MB << 25.7 MB out); attn
  // later overwrites every out element and reads nothing from out.
  char* oscr = (char*)d_out;
  const size_t FSZ = (size_t)8 * NQPAD * DIM * 2;      // 6,815,744
  const size_t WSZ = (size_t)1536 * DIM * 2;           // 786,432
  u16* fmapT = (u16*)oscr;
  u16* Wbf   = (u16*)(oscr + FSZ);
  float* emb = (float*)(oscr + FSZ + WSZ);

  emb_kernel<<<dim3(784), dim3(256), 0, stream>>>(pf, ph, pw, emb);
  wconv_kernel<<<dim3(192), dim3(256), 0, stream>>>(W, Wbf);
  ftrans_kernel<<<dim3(26, 4, 8), dim3(256), 0, stream>>>(fmap, fmapT);
  proj_kernel<<<dim3(1248), dim3(256), 0, stream>>>(Wbf, fmapT, emb, qws, tiles);
  attn_kernel<<<dim3(416), dim3(512), 0, stream>>>(qws, tiles, out);
}

// Round 7
// 145.362 us; speedup vs baseline: 1.0490x; 1.0490x over previous
//
#include <hip/hip_runtime.h>
#include <hip/hip_bf16.h>
#include <cstdint>

#define NPOS 1568   // 8*14*14
#define NQPAD 1664  // 13 * 128
#define NKVT 25     // kv tiles of 64
#define DHEAD 128
#define DIM 256
// scale * log2(e): softmax in log2 domain
#define SCALE_Q (0.08838834764831845f * 1.4426950408889634f)

typedef __bf16 bf16x8 __attribute__((ext_vector_type(8)));
typedef float f32x4 __attribute__((ext_vector_type(4)));
typedef float f32x16 __attribute__((ext_vector_type(16)));
typedef unsigned short u16;
typedef u16 u16x8 __attribute__((ext_vector_type(8)));

__device__ __forceinline__ unsigned cvtpk(float a, float b) {
  unsigned r;
  asm("v_cvt_pk_bf16_f32 %0, %1, %2" : "=v"(r) : "v"(a), "v"(b));
  return r;
}

__device__ __forceinline__ f32x16 zero16() {
  f32x16 v;
#pragma unroll
  for (int i = 0; i < 16; ++i) v[i] = 0.f;
  return v;
}

// ---------------- emb: [1568][128] f32 ----------------
__global__ __launch_bounds__(256) void emb_kernel(
    const float* __restrict__ pf, const float* __restrict__ ph,
    const float* __restrict__ pw, float* __restrict__ emb) {
  int idx = blockIdx.x * 256 + threadIdx.x;
  int pos = idx >> 7, d = idx & 127;
  int jf = pos / 196; int r = pos - jf * 196; int jh = r / 14; int jw = r - jh * 14;
  emb[idx] = pf[jf * 128 + d] + ph[jh * 128 + d] + pw[jw * 128 + d];
}

// ---------------- wconv: W f32 -> bf16, same layout [1536][256] ----------------
__global__ __launch_bounds__(256) void wconv_kernel(
    const float* __restrict__ W, u16* __restrict__ Wbf) {
  int i8 = (blockIdx.x * 256 + threadIdx.x) * 8;
  float4 f0 = *(const float4*)(W + i8);
  float4 f1 = *(const float4*)(W + i8 + 4);
  union { unsigned u[4]; u16x8 v; } o;
  o.u[0] = cvtpk(f0.x, f0.y); o.u[1] = cvtpk(f0.z, f0.w);
  o.u[2] = cvtpk(f1.x, f1.y); o.u[3] = cvtpk(f1.z, f1.w);
  *(u16x8*)(Wbf + i8) = o.v;
}

// ---------------- ftrans: fmap [b][c][pos] f32 -> fmapT [b][pos(pad 1664)][c] bf16 ----------------
// grid (26, 4, 8)
__global__ __launch_bounds__(256) void ftrans_kernel(
    const float* __restrict__ fmap, u16* __restrict__ fmapT) {
  __shared__ float t[64][68];
  const int tid = threadIdx.x;
  const int pos0 = blockIdx.x * 64, c0 = blockIdx.y * 64, b = blockIdx.z;
  const int cl = tid >> 3, p8 = (tid & 7) * 8;
  const bool pv = (pos0 + p8) < NPOS;   // NPOS % 8 == 0 -> all-or-nothing
#pragma unroll
  for (int half = 0; half < 2; ++half) {
    int c = cl + half * 32;
    float4 f0 = {0.f, 0.f, 0.f, 0.f}, f1 = {0.f, 0.f, 0.f, 0.f};
    if (pv) {
      const float* src = fmap + ((size_t)(b * DIM + c0 + c)) * NPOS + pos0 + p8;
      f0 = *(const float4*)src;
      f1 = *(const float4*)(src + 4);
    }
    *(float4*)&t[c][p8] = f0;
    *(float4*)&t[c][p8 + 4] = f1;
  }
  __syncthreads();
  const int pl = tid >> 2, c16 = (tid & 3) * 16;
  const int gpos = pos0 + pl;
  union { unsigned u[8]; } o;
  if (gpos < NPOS) {
#pragma unroll
    for (int i = 0; i < 8; ++i) o.u[i] = cvtpk(t[c16 + 2 * i][pl], t[c16 + 2 * i + 1][pl]);
  } else {
#pragma unroll
    for (int i = 0; i < 8; ++i) o.u[i] = 0;
  }
  u16* dst = fmapT + ((size_t)b * NQPAD + gpos) * DIM + c0 + c16;
  *(uint4*)(dst) = *(uint4*)&o.u[0];
  *(uint4*)(dst + 8) = *(uint4*)&o.u[4];
}

// ---------------- projection: 128x128 tiles, frags direct from L2 ----------------
// flat grid 1248: b = wid&7 (XCD-local), then 12 o-tiles x 13 pos-tiles.
// K/V are emitted as MFMA-FRAG-ORDER tile images (32KB per 64-key tile):
//   K:  [grp2][kk8][lane64][16B]  lane slot (hi*32+l31) holds K[grp*32+rho(l31)][kk*16+8hi+0..7]
//   V:  +16KB [grp2][dt4][kj2][lane64][16B]  slot holds V^T[dt*32+l31][grp*32+kj*16+8hi+0..7]
__global__ __launch_bounds__(256, 4) void proj_kernel(
    const u16* __restrict__ Wbf, const u16* __restrict__ fmapT,
    const float* __restrict__ emb, u16* __restrict__ qws, char* __restrict__ tiles) {
  __shared__ float ot[64][132];
  const int tid = threadIdx.x;
  const int lane = tid & 63, w = tid >> 6;
  const int l15 = lane & 15, g = lane >> 4;
  const int wid = blockIdx.x;
  const int b = wid & 7;
  const int gq = wid >> 3;              // 0..155
  const int o0 = (gq / 13) * 128;
  const int pos0 = (gq % 13) * 128;
  const int wo = (w & 1) * 64, wp = (w >> 1) * 64;

  f32x4 acc[4][4];
#pragma unroll
  for (int i = 0; i < 4; ++i)
#pragma unroll
    for (int j = 0; j < 4; ++j) acc[i][j] = (f32x4){0.f, 0.f, 0.f, 0.f};

  const u16* Ab = Wbf + (size_t)(o0 + wo + l15) * DIM + g * 8;
  const u16* Bb = fmapT + ((size_t)b * NQPAD + pos0 + wp + l15) * DIM + g * 8;
#pragma unroll 2
  for (int c0 = 0; c0 < DIM; c0 += 32) {
    bf16x8 a[4], bb[4];
#pragma unroll
    for (int t = 0; t < 4; ++t) a[t] = *(const bf16x8*)(Ab + (size_t)t * 16 * DIM + c0);
#pragma unroll
    for (int t = 0; t < 4; ++t) bb[t] = *(const bf16x8*)(Bb + (size_t)t * 16 * DIM + c0);
#pragma unroll
    for (int i = 0; i < 4; ++i)
#pragma unroll
      for (int j = 0; j < 4; ++j)
        acc[i][j] = __builtin_amdgcn_mfma_f32_16x16x32_bf16(a[i], bb[j], acc[i][j], 0, 0, 0);
  }

  const int sec = o0 >> 9, head = (o0 >> 7) & 3, bh = b * 4 + head;

  if (sec < 2) {   // q,k: transpose to [pos][o] chunks of 64 pos
#pragma unroll
    for (int ph = 0; ph < 2; ++ph) {
      __syncthreads();
      if (wp == ph * 64) {
#pragma unroll
        for (int i = 0; i < 4; ++i)
#pragma unroll
          for (int j = 0; j < 4; ++j)
#pragma unroll
            for (int r = 0; r < 4; ++r)
              ot[j * 16 + l15][wo + i * 16 + 4 * g + r] = acc[i][j][r];
      }
      __syncthreads();
      const int pl = tid >> 2, c32 = (tid & 3) * 32;
      const int gpos = pos0 + ph * 64 + pl;
      float v[32];
#pragma unroll
      for (int i = 0; i < 32; ++i) v[i] = ot[pl][c32 + i];
      if (sec == 0) {
#pragma unroll
        for (int q = 0; q < 4; ++q) {
          union { unsigned u[4]; u16x8 h; } o8;
#pragma unroll
          for (int i = 0; i < 4; ++i)
            o8.u[i] = cvtpk(v[q * 8 + 2 * i] * SCALE_Q, v[q * 8 + 2 * i + 1] * SCALE_Q);
          *(u16x8*)(qws + ((size_t)bh * NQPAD + gpos) * DHEAD + c32 + q * 8) = o8.h;
        }
      } else {
        if (gpos < NKVT * 64) {
          if (gpos < NPOS) {
            const float* eb = emb + (size_t)gpos * DHEAD + c32;
#pragma unroll
            for (int i = 0; i < 8; ++i) {
              float4 e = *(const float4*)(eb + i * 4);
              v[i * 4 + 0] += e.x; v[i * 4 + 1] += e.y;
              v[i * 4 + 2] += e.z; v[i * 4 + 3] += e.w;
            }
          }
          const int jt = gpos >> 6, jl = gpos & 63;
          const int grp = jl >> 5, jl31 = jl & 31;
          const int l31s = (jl31 & 0x13) | ((jl31 & 4) << 1) | ((jl31 & 8) >> 1);  // rho
          char* tb = tiles + ((size_t)(bh * NKVT + jt)) * 32768 + grp * 8192;
#pragma unroll
          for (int q = 0; q < 4; ++q) {
            union { unsigned u[4]; u16x8 h; } o8;
#pragma unroll
            for (int i = 0; i < 4; ++i)
              o8.u[i] = cvtpk(v[q * 8 + 2 * i], v[q * 8 + 2 * i + 1]);
            const int c = c32 + q * 8;
            const int kk = c >> 4, hi = (c >> 3) & 1;
            *(u16x8*)(tb + kk * 1024 + (hi * 32 + l31s) * 16) = o8.h;
          }
        }
      }
    }
  } else {         // v: keep [d][pos], chunks of 64 d -> frag-order image
#pragma unroll
    for (int ch = 0; ch < 2; ++ch) {
      __syncthreads();
      if (wo == ch * 64) {
#pragma unroll
        for (int i = 0; i < 4; ++i)
#pragma unroll
          for (int j = 0; j < 4; ++j)
#pragma unroll
            for (int r = 0; r < 4; ++r)
              ot[i * 16 + 4 * g + r][wp + j * 16 + l15] = acc[i][j][r];
      }
      __syncthreads();
      const int dl = tid >> 2, p32 = (tid & 3) * 32;
      const int d = ch * 64 + dl;
      const int gp = pos0 + p32;
      float v[32];
#pragma unroll
      for (int i = 0; i < 32; ++i) v[i] = ot[dl][p32 + i];
      if (gp < NKVT * 64) {
        const int jt = gp >> 6, jl0 = gp & 63;
        const int dt = d >> 5, dl31 = d & 31;
        char* tb = tiles + ((size_t)(bh * NKVT + jt)) * 32768 + 16384;
#pragma unroll
        for (int q = 0; q < 4; ++q) {
          union { unsigned u[4]; u16x8 h; } o8;
#pragma unroll
          for (int i = 0; i < 4; ++i)
            o8.u[i] = cvtpk(v[q * 8 + 2 * i], v[q * 8 + 2 * i + 1]);
          const int jl = jl0 + q * 8;
          const int grp = jl >> 5, kj = (jl >> 4) & 1, hi2 = (jl >> 3) & 1;
          *(u16x8*)(tb + grp * 8192 + dt * 2048 + kj * 1024 + (hi2 * 32 + dl31) * 16) = o8.h;
        }
      }
    }
  }
}

// ---------------- attention: LDS-free streaming, 4 waves (2 qw x 2 grp) ----------------
// flat grid 832: bh = (wid&7)*4 + (wid>>3)/26, qt = (wid>>3)%26. All K/V reads are
// coalesced 1KB dwordx4 from frag-order tile images (L1/L2-resident); no barriers
// in the KV loop, no LDS except the final flash-merge.
__global__ __launch_bounds__(256, 2) void attn_kernel(
    const u16* __restrict__ qws, const char* __restrict__ tiles,
    float* __restrict__ out) {
  __shared__ float ml[2 * 64 * 2];   // [qw][lane][{m,l}]
  __shared__ float cx[32 * 128];     // merge exchange, 16KB
  const int tid = threadIdx.x;
  const int lane = tid & 63, w = tid >> 6;
  const int qw = w & 1, grp = w >> 1;
  const int l31 = lane & 31, hi = lane >> 5;
  const int wid = blockIdx.x;
  const int bh = (wid & 7) * 4 + (wid >> 3) / 26;
  const int qt = (wid >> 3) % 26;
  const int b = bh >> 2, h = bh & 3;
  const int q0 = qt * 64;

  // Q B-frags: q = q0 + 32qw + l31, d = kk*16 + 8hi + i  (pad rows are zero)
  bf16x8 qf[8];
  {
    const u16* qp = qws + ((size_t)bh * NQPAD + q0 + qw * 32 + l31) * DHEAD + 8 * hi;
#pragma unroll
    for (int kk = 0; kk < 8; ++kk) qf[kk] = *(const bf16x8*)(qp + kk * 16);
  }

  f32x16 oacc[4];
#pragma unroll
  for (int dt = 0; dt < 4; ++dt) oacc[dt] = zero16();
  float m = -1e30f, l = 0.f;

  const char* kb = tiles + (size_t)bh * NKVT * 32768 + grp * 8192 + lane * 16;
  const char* vb = kb + 16384;

  for (int jt = 0; jt < NKVT; ++jt) {
    if (grp == 0 || jt < NKVT - 1) {   // tail tile: only rows 0..31 valid (grp 0)
      bf16x8 ka[8];
#pragma unroll
      for (int kk = 0; kk < 8; ++kk) ka[kk] = *(const bf16x8*)(kb + kk * 1024);
      bf16x8 va[4][2];
#pragma unroll
      for (int dt = 0; dt < 4; ++dt)
#pragma unroll
        for (int kj = 0; kj < 2; ++kj)
          va[dt][kj] = *(const bf16x8*)(vb + dt * 2048 + kj * 1024);

      // S^T = mfma(K, Q): sc[r] = S[q=l31][grp*32 + 16*(r>>3) + 8*hi + (r&7)]
      f32x16 sc = zero16();
#pragma unroll
      for (int kk = 0; kk < 8; ++kk)
        sc = __builtin_amdgcn_mfma_f32_32x32x16_bf16(ka[kk], qf[kk], sc, 0, 0, 0);

      float pm = -1e30f;
#pragma unroll
      for (int i = 0; i < 16; ++i) pm = fmaxf(pm, sc[i]);
      pm = fmaxf(pm, __shfl_xor(pm, 32));
      if (!__all(pm <= m + 8.f)) {   // defer-max
        float mn = fmaxf(m, pm);
        float al = exp2f(m - mn);
        m = mn;
        l *= al;
#pragma unroll
        for (int dt = 0; dt < 4; ++dt)
#pragma unroll
          for (int i = 0; i < 16; ++i) oacc[dt][i] *= al;
      }
      float lac = 0.f;
#pragma unroll
      for (int i = 0; i < 16; ++i) { sc[i] = exp2f(sc[i] - m); lac += sc[i]; }
      l += lac;

      union { unsigned u[4]; bf16x8 v; } pb0, pb1;
      pb0.u[0] = cvtpk(sc[0], sc[1]);   pb0.u[1] = cvtpk(sc[2], sc[3]);
      pb0.u[2] = cvtpk(sc[4], sc[5]);   pb0.u[3] = cvtpk(sc[6], sc[7]);
      pb1.u[0] = cvtpk(sc[8], sc[9]);   pb1.u[1] = cvtpk(sc[10], sc[11]);
      pb1.u[2] = cvtpk(sc[12], sc[13]); pb1.u[3] = cvtpk(sc[14], sc[15]);
#pragma unroll
      for (int dt = 0; dt < 4; ++dt) {
        oacc[dt] = __builtin_amdgcn_mfma_f32_32x32x16_bf16(va[dt][0], pb0.v, oacc[dt], 0, 0, 0);
        oacc[dt] = __builtin_amdgcn_mfma_f32_32x32x16_bf16(va[dt][1], pb1.v, oacc[dt], 0, 0, 0);
      }
    }
    kb += 32768; vb += 32768;
  }

  // ---- combine hi-halves of l, then flash-merge grp 1 into grp 0, store ----
  float lt = l + __shfl_xor(l, 32);
  if (grp == 1) {
    ml[(qw * 64 + lane) * 2 + 0] = m;
    ml[(qw * 64 + lane) * 2 + 1] = lt;
  }
  __syncthreads();
  float fA = 0.f, fB = 0.f;
  if (grp == 0) {
    float mB = ml[(qw * 64 + lane) * 2 + 0];
    float lB = ml[(qw * 64 + lane) * 2 + 1];
    float ms = fmaxf(m, mB);
    float aA = exp2f(m - ms), aB = exp2f(mB - ms);
    float inv = 1.f / (lt * aA + lB * aB);
    fA = aA * inv; fB = aB * inv;
  }
  const int q = q0 + qw * 32 + l31;
  float* ob = out + (size_t)(b * 512 + h * 128) * NPOS + q;
#pragma unroll
  for (int ch = 0; ch < 2; ++ch) {
    __syncthreads();
    if (grp == 1) {
#pragma unroll
      for (int k = 0; k < 2; ++k)
#pragma unroll
        for (int i = 0; i < 16; ++i)
          cx[(k * 16 + i) * 128 + qw * 64 + lane] = oacc[ch * 2 + k][i];
    }
    __syncthreads();
    if (grp == 0 && q < NPOS) {
#pragma unroll
      for (int k = 0; k < 2; ++k) {
        const int dt = ch * 2 + k;
#pragma unroll
        for (int r = 0; r < 16; ++r) {
          float vB = cx[(k * 16 + r) * 128 + qw * 64 + lane];
          float vo = oacc[dt][r] * fA + vB * fB;
          int d = dt * 32 + (r & 3) + 8 * (r >> 2) + 4 * hi;
          ob[(size_t)d * NPOS] = vo;
        }
      }
    }
  }
}

extern "C" void kernel_launch(void* const* d_in, const int* in_sizes, int n_in,
                              void* d_out, int out_size, void* d_ws, size_t ws_size,
                              hipStream_t stream) {
  const float* fmap = (const float*)d_in[0];
  const float* W    = (const float*)d_in[1];
  const float* pf   = (const float*)d_in[2];
  const float* ph   = (const float*)d_in[3];
  const float* pw   = (const float*)d_in[4];
  float* out = (float*)d_out;

  // ws holds only qws + tiles (39.85 MB, within the R3-proven budget).
  char* ws = (char*)d_ws;
  const size_t QSZ = (size_t)32 * NQPAD * DHEAD * 2;   // 13,631,488
  u16* qws    = (u16*)ws;
  char* tiles = ws + QSZ;

  // Aux buffers live in d_out-as-scratch (8.4 MB << 25.7 MB out); attn
  // later overwrites every out element and reads nothing from out.
  char* oscr = (char*)d_out;
  const size_t FSZ = (size_t)8 * NQPAD * DIM * 2;      // 6,815,744
  const size_t WSZ = (size_t)1536 * DIM * 2;           // 786,432
  u16* fmapT = (u16*)oscr;
  u16* Wbf   = (u16*)(oscr + FSZ);
  float* emb = (float*)(oscr + FSZ + WSZ);

  emb_kernel<<<dim3(784), dim3(256), 0, stream>>>(pf, ph, pw, emb);
  wconv_kernel<<<dim3(192), dim3(256), 0, stream>>>(W, Wbf);
  ftrans_kernel<<<dim3(26, 4, 8), dim3(256), 0, stream>>>(fmap, fmapT);
  proj_kernel<<<dim3(1248), dim3(256), 0, stream>>>(Wbf, fmapT, emb, qws, tiles);
  attn_kernel<<<dim3(832), dim3(256), 0, stream>>>(qws, tiles, out);
}

// Round 9
// 144.056 us; speedup vs baseline: 1.0585x; 1.0091x over previous
//
#include <hip/hip_runtime.h>
#include <hip/hip_bf16.h>
#include <cstdint>

#define NPOS 1568   // 8*14*14
#define NQPAD 1664  // 13 * 128
#define NKVT 25     // kv tiles of 64
#define DHEAD 128
#define DIM 256
// scale * log2(e): softmax in log2 domain
#define SCALE_Q (0.08838834764831845f * 1.4426950408889634f)

typedef __bf16 bf16x8 __attribute__((ext_vector_type(8)));
typedef float f32x4 __attribute__((ext_vector_type(4)));
typedef float f32x16 __attribute__((ext_vector_type(16)));
typedef unsigned short u16;
typedef u16 u16x8 __attribute__((ext_vector_type(8)));

__device__ __forceinline__ unsigned cvtpk(float a, float b) {
  unsigned r;
  asm("v_cvt_pk_bf16_f32 %0, %1, %2" : "=v"(r) : "v"(a), "v"(b));
  return r;
}

__device__ __forceinline__ f32x16 zero16() {
  f32x16 v;
#pragma unroll
  for (int i = 0; i < 16; ++i) v[i] = 0.f;
  return v;
}

// ---------------- emb: [1568][128] f32 ----------------
__global__ __launch_bounds__(256) void emb_kernel(
    const float* __restrict__ pf, const float* __restrict__ ph,
    const float* __restrict__ pw, float* __restrict__ emb) {
  int idx = blockIdx.x * 256 + threadIdx.x;
  int pos = idx >> 7, d = idx & 127;
  int jf = pos / 196; int r = pos - jf * 196; int jh = r / 14; int jw = r - jh * 14;
  emb[idx] = pf[jf * 128 + d] + ph[jh * 128 + d] + pw[jw * 128 + d];
}

// ---------------- wconv: W f32 -> bf16, same layout [1536][256] ----------------
__global__ __launch_bounds__(256) void wconv_kernel(
    const float* __restrict__ W, u16* __restrict__ Wbf) {
  int i8 = (blockIdx.x * 256 + threadIdx.x) * 8;
  float4 f0 = *(const float4*)(W + i8);
  float4 f1 = *(const float4*)(W + i8 + 4);
  union { unsigned u[4]; u16x8 v; } o;
  o.u[0] = cvtpk(f0.x, f0.y); o.u[1] = cvtpk(f0.z, f0.w);
  o.u[2] = cvtpk(f1.x, f1.y); o.u[3] = cvtpk(f1.z, f1.w);
  *(u16x8*)(Wbf + i8) = o.v;
}

// ---------------- ftrans: fmap [b][c][pos] f32 -> fmapT [b][pos(pad 1664)][c] bf16 ----------------
// grid (26, 4, 8)
__global__ __launch_bounds__(256) void ftrans_kernel(
    const float* __restrict__ fmap, u16* __restrict__ fmapT) {
  __shared__ float t[64][68];
  const int tid = threadIdx.x;
  const int pos0 = blockIdx.x * 64, c0 = blockIdx.y * 64, b = blockIdx.z;
  const int cl = tid >> 3, p8 = (tid & 7) * 8;
  const bool pv = (pos0 + p8) < NPOS;   // NPOS % 8 == 0 -> all-or-nothing
#pragma unroll
  for (int half = 0; half < 2; ++half) {
    int c = cl + half * 32;
    float4 f0 = {0.f, 0.f, 0.f, 0.f}, f1 = {0.f, 0.f, 0.f, 0.f};
    if (pv) {
      const float* src = fmap + ((size_t)(b * DIM + c0 + c)) * NPOS + pos0 + p8;
      f0 = *(const float4*)src;
      f1 = *(const float4*)(src + 4);
    }
    *(float4*)&t[c][p8] = f0;
    *(float4*)&t[c][p8 + 4] = f1;
  }
  __syncthreads();
  const int pl = tid >> 2, c16 = (tid & 3) * 16;
  const int gpos = pos0 + pl;
  union { unsigned u[8]; } o;
  if (gpos < NPOS) {
#pragma unroll
    for (int i = 0; i < 8; ++i) o.u[i] = cvtpk(t[c16 + 2 * i][pl], t[c16 + 2 * i + 1][pl]);
  } else {
#pragma unroll
    for (int i = 0; i < 8; ++i) o.u[i] = 0;
  }
  u16* dst = fmapT + ((size_t)b * NQPAD + gpos) * DIM + c0 + c16;
  *(uint4*)(dst) = *(uint4*)&o.u[0];
  *(uint4*)(dst + 8) = *(uint4*)&o.u[4];
}

// ---------------- projection: 128x128 tiles, frags direct from L2 ----------------
// flat grid 1248: b = wid&7 (XCD-local), then 12 o-tiles x 13 pos-tiles.
// K/V emitted as MFMA-frag-order tile images (32KB per 64-key tile):
//   K:  [grp2][kk8][slot64][16B]  slot s holds K[jt*64+grp*32+rho(s&31)][kk*16+(s>>5)*8+0..7]
//   V:  +16KB [grp2][dt4][kj2][slot64][16B]  slot s holds V^T[dt*32+(s&31)][jt*64+grp*32+kj*16+(s>>5)*8+0..7]
__global__ __launch_bounds__(256, 3) void proj_kernel(
    const u16* __restrict__ Wbf, const u16* __restrict__ fmapT,
    const float* __restrict__ emb, u16* __restrict__ qws, char* __restrict__ tiles) {
  __shared__ float ot[64][132];
  const int tid = threadIdx.x;
  const int lane = tid & 63, w = tid >> 6;
  const int l15 = lane & 15, g = lane >> 4;
  const int wid = blockIdx.x;
  const int b = wid & 7;
  const int gq = wid >> 3;              // 0..155
  const int o0 = (gq / 13) * 128;
  const int pos0 = (gq % 13) * 128;
  const int wo = (w & 1) * 64, wp = (w >> 1) * 64;

  f32x4 acc[4][4];
#pragma unroll
  for (int i = 0; i < 4; ++i)
#pragma unroll
    for (int j = 0; j < 4; ++j) acc[i][j] = (f32x4){0.f, 0.f, 0.f, 0.f};

  const u16* Ab = Wbf + (size_t)(o0 + wo + l15) * DIM + g * 8;
  const u16* Bb = fmapT + ((size_t)b * NQPAD + pos0 + wp + l15) * DIM + g * 8;

  // 2-deep software pipeline, static buffer parity via full unroll
  bf16x8 a[2][4], bb[2][4];
#pragma unroll
  for (int t = 0; t < 4; ++t) {
    a[0][t]  = *(const bf16x8*)(Ab + (size_t)t * 16 * DIM);
    bb[0][t] = *(const bf16x8*)(Bb + (size_t)t * 16 * DIM);
  }
#pragma unroll
  for (int st = 0; st < 8; ++st) {
    const int cur = st & 1, nxt = cur ^ 1;
    if (st < 7) {
#pragma unroll
      for (int t = 0; t < 4; ++t) {
        a[nxt][t]  = *(const bf16x8*)(Ab + (size_t)t * 16 * DIM + (st + 1) * 32);
        bb[nxt][t] = *(const bf16x8*)(Bb + (size_t)t * 16 * DIM + (st + 1) * 32);
      }
    }
#pragma unroll
    for (int i = 0; i < 4; ++i)
#pragma unroll
      for (int j = 0; j < 4; ++j)
        acc[i][j] = __builtin_amdgcn_mfma_f32_16x16x32_bf16(a[cur][i], bb[cur][j], acc[i][j], 0, 0, 0);
  }

  const int sec = o0 >> 9, head = (o0 >> 7) & 3, bh = b * 4 + head;

  if (sec < 2) {   // q,k: per 64-pos phase, transpose to ot[pos][o] then coalesced stores
#pragma unroll
    for (int ph = 0; ph < 2; ++ph) {
      __syncthreads();
      if (wp == ph * 64) {
#pragma unroll
        for (int i = 0; i < 4; ++i)
#pragma unroll
          for (int j = 0; j < 4; ++j)
#pragma unroll
            for (int r = 0; r < 4; ++r)
              ot[j * 16 + l15][wo + i * 16 + 4 * g + r] = acc[i][j][r];
      }
      __syncthreads();
      if (sec == 0) {
        // q: thread -> (row p, 16B seg); lanes fill rows contiguously
#pragma unroll
        for (int it = 0; it < 4; ++it) {
          const int p = it * 16 + (tid >> 4), d0 = (tid & 15) * 8;
          const int gpos = pos0 + ph * 64 + p;
          const float* r = &ot[p][d0];
          union { unsigned u[4]; u16x8 h; } o8;
#pragma unroll
          for (int i = 0; i < 4; ++i)
            o8.u[i] = cvtpk(r[2 * i] * SCALE_Q, r[2 * i + 1] * SCALE_Q);
          *(u16x8*)(qws + ((size_t)bh * NQPAD + gpos) * DHEAD + d0) = o8.h;
        }
      } else {
        // k: fill the frag-order image; consecutive threads -> consecutive slots
        const int jt = (pos0 >> 6) + ph;
        if (jt < NKVT) {
          char* tb = tiles + ((size_t)(bh * NKVT + jt)) * 32768;
#pragma unroll
          for (int u = 0; u < 4; ++u) {
            const int L = u * 256 + tid;            // 0..1023
            const int grp = L >> 9, kk = (L >> 6) & 7, s = L & 63;
            const int sl = s & 31, hi2 = s >> 5;
            const int rr = (sl & 0x13) | ((sl & 4) << 1) | ((sl & 8) >> 1);  // rho
            const int row = grp * 32 + rr;
            const int d0 = kk * 16 + hi2 * 8;
            const int gpos = pos0 + ph * 64 + row;
            float vv[8];
#pragma unroll
            for (int i = 0; i < 8; ++i) vv[i] = ot[row][d0 + i];
            if (gpos < NPOS) {
              const float* eb = emb + (size_t)gpos * DHEAD + d0;
#pragma unroll
              for (int i = 0; i < 8; ++i) vv[i] += eb[i];
            }
            union { unsigned u4[4]; u16x8 h; } o8;
#pragma unroll
            for (int i = 0; i < 4; ++i) o8.u4[i] = cvtpk(vv[2 * i], vv[2 * i + 1]);
            *(u16x8*)(tb + grp * 8192 + kk * 1024 + s * 16) = o8.h;
          }
        }
      }
    }
  } else {         // v: per 64-d phase, ot[d][pos], coalesced frag-image stores
#pragma unroll
    for (int ch = 0; ch < 2; ++ch) {
      __syncthreads();
      if (wo == ch * 64) {
#pragma unroll
        for (int i = 0; i < 4; ++i)
#pragma unroll
          for (int j = 0; j < 4; ++j)
#pragma unroll
            for (int r = 0; r < 4; ++r)
              ot[i * 16 + 4 * g + r][wp + j * 16 + l15] = acc[i][j][r];
      }
      __syncthreads();
      const int jt0 = pos0 >> 6;
#pragma unroll
      for (int u = 0; u < 4; ++u) {
        const int L = u * 256 + tid;                // 0..1023
        const int jtl = L >> 9, grp = (L >> 8) & 1, dtl = (L >> 7) & 1;
        const int kj = (L >> 6) & 1, s = L & 63;
        const int jt = jt0 + jtl;
        if (jt < NKVT) {
          const int drow = dtl * 32 + (s & 31);
          const int pcol = jtl * 64 + grp * 32 + kj * 16 + (s >> 5) * 8;
          float vv[8];
#pragma unroll
          for (int i = 0; i < 8; ++i) vv[i] = ot[drow][pcol + i];
          union { unsigned u4[4]; u16x8 h; } o8;
#pragma unroll
          for (int i = 0; i < 4; ++i) o8.u4[i] = cvtpk(vv[2 * i], vv[2 * i + 1]);
          *(u16x8*)(tiles + ((size_t)(bh * NKVT + jt)) * 32768 + 16384 +
                    grp * 8192 + (2 * ch + dtl) * 2048 + kj * 1024 + s * 16) = o8.h;
        }
      }
    }
  }
}

// ---------------- attention: LDS-free streaming, 4 waves (2 qw x 2 grp) ----------------
// EXACT R7 version (passed, 81 us) — reverted for bisection.
__global__ __launch_bounds__(256, 2) void attn_kernel(
    const u16* __restrict__ qws, const char* __restrict__ tiles,
    float* __restrict__ out) {
  __shared__ float ml[2 * 64 * 2];   // [qw][lane][{m,l}]
  __shared__ float cx[32 * 128];     // merge exchange, 16KB
  const int tid = threadIdx.x;
  const int lane = tid & 63, w = tid >> 6;
  const int qw = w & 1, grp = w >> 1;
  const int l31 = lane & 31, hi = lane >> 5;
  const int wid = blockIdx.x;
  const int bh = (wid & 7) * 4 + (wid >> 3) / 26;
  const int qt = (wid >> 3) % 26;
  const int b = bh >> 2, h = bh & 3;
  const int q0 = qt * 64;

  // Q B-frags: q = q0 + 32qw + l31, d = kk*16 + 8hi + i  (pad rows are zero)
  bf16x8 qf[8];
  {
    const u16* qp = qws + ((size_t)bh * NQPAD + q0 + qw * 32 + l31) * DHEAD + 8 * hi;
#pragma unroll
    for (int kk = 0; kk < 8; ++kk) qf[kk] = *(const bf16x8*)(qp + kk * 16);
  }

  f32x16 oacc[4];
#pragma unroll
  for (int dt = 0; dt < 4; ++dt) oacc[dt] = zero16();
  float m = -1e30f, l = 0.f;

  const char* kb = tiles + (size_t)bh * NKVT * 32768 + grp * 8192 + lane * 16;
  const char* vb = kb + 16384;

  for (int jt = 0; jt < NKVT; ++jt) {
    if (grp == 0 || jt < NKVT - 1) {   // tail tile: only rows 0..31 valid (grp 0)
      bf16x8 ka[8];
#pragma unroll
      for (int kk = 0; kk < 8; ++kk) ka[kk] = *(const bf16x8*)(kb + kk * 1024);
      bf16x8 va[4][2];
#pragma unroll
      for (int dt = 0; dt < 4; ++dt)
#pragma unroll
        for (int kj = 0; kj < 2; ++kj)
          va[dt][kj] = *(const bf16x8*)(vb + dt * 2048 + kj * 1024);

      // S^T = mfma(K, Q): sc[r] = S[q=l31][grp*32 + 16*(r>>3) + 8*hi + (r&7)]
      f32x16 sc = zero16();
#pragma unroll
      for (int kk = 0; kk < 8; ++kk)
        sc = __builtin_amdgcn_mfma_f32_32x32x16_bf16(ka[kk], qf[kk], sc, 0, 0, 0);

      float pm = -1e30f;
#pragma unroll
      for (int i = 0; i < 16; ++i) pm = fmaxf(pm, sc[i]);
      pm = fmaxf(pm, __shfl_xor(pm, 32));
      if (!__all(pm <= m + 8.f)) {   // defer-max
        float mn = fmaxf(m, pm);
        float al = exp2f(m - mn);
        m = mn;
        l *= al;
#pragma unroll
        for (int dt = 0; dt < 4; ++dt)
#pragma unroll
          for (int i = 0; i < 16; ++i) oacc[dt][i] *= al;
      }
      float lac = 0.f;
#pragma unroll
      for (int i = 0; i < 16; ++i) { sc[i] = exp2f(sc[i] - m); lac += sc[i]; }
      l += lac;

      union { unsigned u[4]; bf16x8 v; } pb0, pb1;
      pb0.u[0] = cvtpk(sc[0], sc[1]);   pb0.u[1] = cvtpk(sc[2], sc[3]);
      pb0.u[2] = cvtpk(sc[4], sc[5]);   pb0.u[3] = cvtpk(sc[6], sc[7]);
      pb1.u[0] = cvtpk(sc[8], sc[9]);   pb1.u[1] = cvtpk(sc[10], sc[11]);
      pb1.u[2] = cvtpk(sc[12], sc[13]); pb1.u[3] = cvtpk(sc[14], sc[15]);
#pragma unroll
      for (int dt = 0; dt < 4; ++dt) {
        oacc[dt] = __builtin_amdgcn_mfma_f32_32x32x16_bf16(va[dt][0], pb0.v, oacc[dt], 0, 0, 0);
        oacc[dt] = __builtin_amdgcn_mfma_f32_32x32x16_bf16(va[dt][1], pb1.v, oacc[dt], 0, 0, 0);
      }
    }
    kb += 32768; vb += 32768;
  }

  // ---- combine hi-halves of l, then flash-merge grp 1 into grp 0, store ----
  float lt = l + __shfl_xor(l, 32);
  if (grp == 1) {
    ml[(qw * 64 + lane) * 2 + 0] = m;
    ml[(qw * 64 + lane) * 2 + 1] = lt;
  }
  __syncthreads();
  float fA = 0.f, fB = 0.f;
  if (grp == 0) {
    float mB = ml[(qw * 64 + lane) * 2 + 0];
    float lB = ml[(qw * 64 + lane) * 2 + 1];
    float ms = fmaxf(m, mB);
    float aA = exp2f(m - ms), aB = exp2f(mB - ms);
    float inv = 1.f / (lt * aA + lB * aB);
    fA = aA * inv; fB = aB * inv;
  }
  const int q = q0 + qw * 32 + l31;
  float* ob = out + (size_t)(b * 512 + h * 128) * NPOS + q;
#pragma unroll
  for (int ch = 0; ch < 2; ++ch) {
    __syncthreads();
    if (grp == 1) {
#pragma unroll
      for (int k = 0; k < 2; ++k)
#pragma unroll
        for (int i = 0; i < 16; ++i)
          cx[(k * 16 + i) * 128 + qw * 64 + lane] = oacc[ch * 2 + k][i];
    }
    __syncthreads();
    if (grp == 0 && q < NPOS) {
#pragma unroll
      for (int k = 0; k < 2; ++k) {
        const int dt = ch * 2 + k;
#pragma unroll
        for (int r = 0; r < 16; ++r) {
          float vB = cx[(k * 16 + r) * 128 + qw * 64 + lane];
          float vo = oacc[dt][r] * fA + vB * fB;
          int d = dt * 32 + (r & 3) + 8 * (r >> 2) + 4 * hi;
          ob[(size_t)d * NPOS] = vo;
        }
      }
    }
  }
}

extern "C" void kernel_launch(void* const* d_in, const int* in_sizes, int n_in,
                              void* d_out, int out_size, void* d_ws, size_t ws_size,
                              hipStream_t stream) {
  const float* fmap = (const float*)d_in[0];
  const float* W    = (const float*)d_in[1];
  const float* pf   = (const float*)d_in[2];
  const float* ph   = (const float*)d_in[3];
  const float* pw   = (const float*)d_in[4];
  float* out = (float*)d_out;

  // ws holds only qws + tiles (39.85 MB, within the R3-proven budget).
  char* ws = (char*)d_ws;
  const size_t QSZ = (size_t)32 * NQPAD * DHEAD * 2;   // 13,631,488
  u16* qws    = (u16*)ws;
  char* tiles = ws + QSZ;

  // Aux buffers live in d_out-as-scratch (8.4 MB << 25.7 MB out); attn
  // later overwrites every out element and reads nothing from out.
  char* oscr = (char*)d_out;
  const size_t FSZ = (size_t)8 * NQPAD * DIM * 2;      // 6,815,744
  const size_t WSZ = (size_t)1536 * DIM * 2;           // 786,432
  u16* fmapT = (u16*)oscr;
  u16* Wbf   = (u16*)(oscr + FSZ);
  float* emb = (float*)(oscr + FSZ + WSZ);

  emb_kernel<<<dim3(784), dim3(256), 0, stream>>>(pf, ph, pw, emb);
  wconv_kernel<<<dim3(192), dim3(256), 0, stream>>>(W, Wbf);
  ftrans_kernel<<<dim3(26, 4, 8), dim3(256), 0, stream>>>(fmap, fmapT);
  proj_kernel<<<dim3(1248), dim3(256), 0, stream>>>(Wbf, fmapT, emb, qws, tiles);
  attn_kernel<<<dim3(832), dim3(256), 0, stream>>>(qws, tiles, out);
}